// Round 8
// baseline (140.571 us; speedup 1.0000x reference)
//
#include <hip/hip_runtime.h>
#include <stdint.h>
#include <math.h>

typedef unsigned short u16;
typedef unsigned int   u32;
typedef __bf16 bf16x8 __attribute__((ext_vector_type(8)));
typedef float  f32x4  __attribute__((ext_vector_type(4)));

#define L_IN 784
#define KPAD 832
#define KT_N 13

__device__ __forceinline__ u32 f2bf(float f){
    u32 u = __float_as_uint(f);
    return (u + 0x7fffu + ((u >> 16) & 1u)) >> 16;   // RNE truncate to bf16
}

__device__ __forceinline__ void gload16(const void* g, void* l){
    __builtin_amdgcn_global_load_lds(
        (const __attribute__((address_space(1))) unsigned char*)g,
        (__attribute__((address_space(3))) unsigned char*)l, 16, 0, 0);
}

// ---------------------------------------------------------------------------
// K0a: W0 [784][128] f32 -> Bimg fragment-broadcast bf16 (validated r6/r7):
// Bimg[((kt*2+kk)*8+nt)*512 + lane*8 + j] = W0[k][col],
//   col = nt*16+(l&15), k = kt*64+kk*32+(l>>4)*8+j. Wave B-load = 1KB contig.
// ---------------------------------------------------------------------------
__global__ void prep_w0(const float* __restrict__ W0, u16* __restrict__ Bimg){
    int idx = blockIdx.x * 256 + threadIdx.x;        // 13*8192 = 106496 total
    if (idx >= KPAD * 128) return;
    int j  = idx & 7;
    int l  = (idx >> 3) & 63;
    int nt = (idx >> 9) & 7;
    int kk = (idx >> 12) & 1;
    int kt = idx >> 13;
    int col = nt * 16 + (l & 15);
    int k   = kt * 64 + kk * 32 + (l >> 4) * 8 + j;
    float v = (k < L_IN) ? W0[k * 128 + col] : 0.f;
    Bimg[idx] = (u16)f2bf(v);
}

// ---------------------------------------------------------------------------
// K0b: Wa/Wb -> fragment-broadcast bf16 image (validated r7).
// ---------------------------------------------------------------------------
__global__ void prep_wab(const float* __restrict__ Wa, const float* __restrict__ Wb,
                         u16* __restrict__ Wab){
    int idx = blockIdx.x * 256 + threadIdx.x;        // 16384 total
    if (idx >= 16384) return;
    int jj  = idx & 7;
    int l   = (idx >> 3) & 63;
    int ks  = (idx >> 9) & 1;
    int nt  = (idx >> 10) & 1;
    int h   = (idx >> 11) & 1;
    int mat = (idx >> 12) & 1;
    int s = ks * 32 + (l >> 4) * 8 + jj;
    int d = nt * 16 + (l & 15);
    const float* W = mat ? Wb : Wa;
    Wab[idx] = (u16)f2bf(W[h * 2048 + s * 32 + d]);
}

// ---------------------------------------------------------------------------
// K1: FUSED relu(h@W0+b0) -> gated attention -> exp -> pooling partials.
// BARRIER-FREE K-loop: each wave stages its OWN 16 rows (4KB) into its OWN
// LDS region via global_load_lds; correctness via per-wave in-order vmcnt:
//   [16 B-loads][4 stage-DMAs]  ->  s_waitcnt vmcnt(20) guarantees the
// PREVIOUS tile's stage (oldest) retired; b0f/b1f waits are vmcnt(12)/(4),
// so the next-tile stage stays in flight across the whole tile.
// Granule-XOR slot = c ^ (row&7) pre-applied on the SOURCE address,
// inverted on the two independent ds_read_b128s (rule 21).
// ---------------------------------------------------------------------------
__global__ __launch_bounds__(256, 4)
void fc_fused(const float* __restrict__ hG, const u16* __restrict__ Bimg,
              const u16* __restrict__ Wab, const float* __restrict__ b0,
              const float* __restrict__ ba, const float* __restrict__ bb,
              const float* __restrict__ Wc, const float* __restrict__ bc,
              float* __restrict__ partials, int N){
    __shared__ __align__(16) char Asm[2][16384];     // [buf][wave region 4KB]
    __shared__ float pbuf[4 * 132];

    const int t    = threadIdx.x;
    const int lane = t & 63;
    const int w    = t >> 6;
    const int lr   = lane & 15;          // A-row / B-col within 16
    const int lk   = lane >> 4;          // k-slot 0..3
    const int gb   = blockIdx.x;
    const long rowBase = (long)gb * 64 + w * 16;     // wave's first row

    // ---- staging geometry: instr j covers local rows j*4+(lane>>4), 16
    // granule-slots/row; slot s of row r holds SOURCE granule s ^ (r&7).
    const int rj   = lane >> 4;                      // 0..3
    const int cswE = (lane & 15) ^ rj;               // src granule, even j
    const float* srcp[4];
    #pragma unroll
    for (int j = 0; j < 4; ++j){
        long grow = rowBase + j * 4 + rj;
        if (grow >= N) grow = N - 1;                 // clamp; e=0 masks later
        srcp[j] = hG + grow * L_IN;
    }
    char* const myA0 = &Asm[0][w * 4096];
    char* const myA1 = &Asm[1][w * 4096];

    f32x4 acc[8];
    #pragma unroll
    for (int nt = 0; nt < 8; ++nt) acc[nt] = (f32x4)0.f;

    auto stage = [&](int kt, char* regn){
        #pragma unroll
        for (int j = 0; j < 4; ++j){
            int csw = cswE ^ ((j & 1) << 2);
            // pad tile: k = kt*64 + csw*4 >= 784 only when kt==12 && csw>=4;
            // clamp to granule 0 (B zero-pads those k).
            int off = kt * 64 + ((kt == KT_N - 1 && csw >= 4) ? 0 : csw * 4);
            gload16(srcp[j] + off, regn + j * 1024 + lane * 16);
        }
    };

    const int m7 = lr & 7;               // read-side XOR
    auto tile = [&](int kt, const char* regn, char* nxt, bool last){
        // ---- all 16 B fragments FIRST (oldest in FIFO) ----
        const u16* bp = Bimg + (size_t)(kt * 2) * 4096 + lane * 8;
        bf16x8 bfr0[8], bfr1[8];
        #pragma unroll
        for (int nt = 0; nt < 8; ++nt) bfr0[nt] = *(const bf16x8*)(bp + nt * 512);
        #pragma unroll
        for (int nt = 0; nt < 8; ++nt) bfr1[nt] = *(const bf16x8*)(bp + 4096 + nt * 512);
        __builtin_amdgcn_sched_barrier(0);
        // ---- stage next tile (youngest: survives all B waits) ----
        if (!last) stage(kt + 1, nxt);
        __builtin_amdgcn_sched_barrier(0);
        // ---- wait: previous stage (oldest) retired; in-order vmcnt ----
        if (last) asm volatile("s_waitcnt vmcnt(16)" ::: "memory");
        else      asm volatile("s_waitcnt vmcnt(20)" ::: "memory");
        __builtin_amdgcn_sched_barrier(0);
        // ---- A from own LDS region (inverse-swizzled), cvt, MFMA ----
        #pragma unroll
        for (int kk = 0; kk < 2; ++kk){
            const int c = kk * 8 + lk * 2;
            f32x4 lo = *(const f32x4*)(regn + lr * 256 + ((c    ) ^ m7) * 16);
            f32x4 hi = *(const f32x4*)(regn + lr * 256 + ((c + 1) ^ m7) * 16);
            bf16x8 af;
            #pragma unroll
            for (int j = 0; j < 4; ++j){
                af[j]     = (__bf16)lo[j];
                af[4 + j] = (__bf16)hi[j];
            }
            #pragma unroll
            for (int nt = 0; nt < 8; ++nt)
                acc[nt] = __builtin_amdgcn_mfma_f32_16x16x32_bf16(
                              af, kk ? bfr1[nt] : bfr0[nt], acc[nt], 0, 0, 0);
        }
    };

    stage(0, myA0);
    #pragma unroll 1
    for (int kt = 0; kt < KT_N - 1; ++kt)
        tile(kt, (kt & 1) ? myA1 : myA0, (kt & 1) ? myA0 : myA1, false);
    tile(KT_N - 1, myA0, myA1, true);    // 12&1==0 -> reads buf0

    // ---- bias + relu; x-tile bf16 into OWN As[0] region (swizzled) ----
    u16* xsw = (u16*)myA0;               // 16 rows x 128 bf16 = 4KB
    #pragma unroll
    for (int nt = 0; nt < 8; ++nt){
        float bias = b0[nt * 16 + lr];
        #pragma unroll
        for (int j = 0; j < 4; ++j){
            float v = acc[nt][j] + bias;
            v = v > 0.f ? v : 0.f;
            acc[nt][j] = v;
            int row = lk * 4 + j;        // local row
            int col = nt * 16 + lr;
            xsw[row * 128 + (((col >> 3) ^ row) << 3) + (col & 7)] = (u16)f2bf(v);
        }
    }
    // per-wave in-order DS: writes above retire before reads below

    // ---- per-head projections via MFMA + logits + exp (validated r7) ----
    float eh[2][4];
    #pragma unroll
    for (int h = 0; h < 2; ++h){
        bf16x8 xa[2];
        #pragma unroll
        for (int ks = 0; ks < 2; ++ks){
            int ch = (h * 8 + ks * 4 + lk) ^ lr;
            xa[ks] = *(const bf16x8*)&xsw[lr * 128 + ch * 8];
        }
        f32x4 Ca[2], Cg[2];
        #pragma unroll
        for (int nt = 0; nt < 2; ++nt){ Ca[nt] = (f32x4)0.f; Cg[nt] = (f32x4)0.f; }
        #pragma unroll
        for (int nt = 0; nt < 2; ++nt)
            #pragma unroll
            for (int ks = 0; ks < 2; ++ks){
                bf16x8 wfa = *(const bf16x8*)(Wab + ((size_t)(h*4 + nt*2 + ks) << 9) + lane * 8);
                bf16x8 wfb = *(const bf16x8*)(Wab + ((size_t)(8 + h*4 + nt*2 + ks) << 9) + lane * 8);
                Ca[nt] = __builtin_amdgcn_mfma_f32_16x16x32_bf16(xa[ks], wfa, Ca[nt], 0, 0, 0);
                Cg[nt] = __builtin_amdgcn_mfma_f32_16x16x32_bf16(xa[ks], wfb, Cg[nt], 0, 0, 0);
            }
        float pj[4];
        #pragma unroll
        for (int j = 0; j < 4; ++j){
            float s = 0.f;
            #pragma unroll
            for (int nt = 0; nt < 2; ++nt){
                int d = h * 32 + nt * 16 + lr;
                float av = tanhf(Ca[nt][j] + ba[d]);
                float gv = 1.f / (1.f + expf(-(Cg[nt][j] + bb[d])));
                s += av * gv * Wc[d];
            }
            pj[j] = s;
        }
        #pragma unroll
        for (int m = 1; m <= 8; m <<= 1)
            #pragma unroll
            for (int j = 0; j < 4; ++j)
                pj[j] += __shfl_xor(pj[j], m, 64);
        #pragma unroll
        for (int j = 0; j < 4; ++j){
            long row = rowBase + lk * 4 + j;
            // |A| <= sum|Wc|+|bc| (~7): exp safe in f32 without max-subtract
            eh[h][j] = (row < (long)N) ? expf(pj[j] + bc[h]) : 0.f;
        }
    }

    // ---- pooling: p[col] = sum over wave's 16 rows of e*x (f32 acc) ----
    float p[8];
    #pragma unroll
    for (int nt = 0; nt < 8; ++nt){
        const int h = nt >> 2;
        float s = 0.f;
        #pragma unroll
        for (int j = 0; j < 4; ++j) s += eh[h][j] * acc[nt][j];
        p[nt] = s;
    }
    #pragma unroll
    for (int m = 16; m <= 32; m <<= 1)
        #pragma unroll
        for (int nt = 0; nt < 8; ++nt)
            p[nt] += __shfl_xor(p[nt], m, 64);
    float es0 = eh[0][0] + eh[0][1] + eh[0][2] + eh[0][3];
    float es1 = eh[1][0] + eh[1][1] + eh[1][2] + eh[1][3];
    es0 += __shfl_xor(es0, 16, 64); es0 += __shfl_xor(es0, 32, 64);
    es1 += __shfl_xor(es1, 16, 64); es1 += __shfl_xor(es1, 32, 64);

    if (lk == 0){
        #pragma unroll
        for (int nt = 0; nt < 8; ++nt)
            pbuf[w * 132 + nt * 16 + lr] = p[nt];
    }
    if (lane == 0){
        pbuf[w * 132 + 128] = es0;
        pbuf[w * 132 + 129] = es1;
    }
    __syncthreads();
    if (t < 130){
        float s = pbuf[t] + pbuf[132 + t] + pbuf[264 + t] + pbuf[396 + t];
        partials[(size_t)gb * 132 + t] = s;
    }
}

// ---------------------------------------------------------------------------
// K2: first-stage reduction over blocks. 128 blocks x 256 threads.
// ---------------------------------------------------------------------------
__global__ __launch_bounds__(256)
void reduce1(const float* __restrict__ partials, float* __restrict__ red, int nb){
    const int b = blockIdx.x, t = threadIdx.x;
    if (t >= 130) return;
    float a = 0.f;
    for (int r = b; r < nb; r += 128)
        a += partials[(size_t)r * 132 + t];
    red[b * 132 + t] = a;
}

// ---------------------------------------------------------------------------
// K3: combine 128 reduced rows (f64), M, logits, sigmoid, Y_hat. One block.
// ---------------------------------------------------------------------------
__global__ __launch_bounds__(256)
void finalize2(const float* __restrict__ red, const float* __restrict__ Wcls,
               const float* __restrict__ bcls, float* __restrict__ out){
    __shared__ double colD[130];
    __shared__ float  M_s[128];
    const int t = threadIdx.x;
    if (t < 130){
        double s = 0.0;
        for (int r = 0; r < 128; ++r) s += (double)red[r * 132 + t];
        colD[t] = s;
    }
    __syncthreads();
    if (t < 128)
        M_s[t] = (float)(colD[t] / colD[128 + (t >> 6)]);
    __syncthreads();
    if (t == 0){
        double lg = (double)bcls[0];
        for (int c = 0; c < 128; ++c) lg += (double)M_s[c] * (double)Wcls[c];
        float pr = (float)(1.0 / (1.0 + exp(-lg)));
        out[0] = pr;
        out[1] = (lg >= 0.0) ? 1.f : 0.f;
    }
}

// ---------------------------------------------------------------------------
extern "C" void kernel_launch(void* const* d_in, const int* in_sizes, int n_in,
                              void* d_out, int out_size, void* d_ws, size_t ws_size,
                              hipStream_t stream){
    const float* hG   = (const float*)d_in[0];
    const float* W0   = (const float*)d_in[1];
    const float* b0   = (const float*)d_in[2];
    const float* Wa   = (const float*)d_in[3];
    const float* ba   = (const float*)d_in[4];
    const float* Wb   = (const float*)d_in[5];
    const float* bb   = (const float*)d_in[6];
    const float* Wc   = (const float*)d_in[7];
    const float* bc   = (const float*)d_in[8];
    const float* Wcls = (const float*)d_in[9];
    const float* bcls = (const float*)d_in[10];

    const int N    = in_sizes[0] / L_IN;
    const int nb64 = (N + 63) / 64;      // 64-row fused tiles

    char* ws = (char*)d_ws;
    u16* Bimg = (u16*)ws;                                  // 212992 B
    u16* Wab  = (u16*)(ws + 262144);                       // 16384 B
    size_t poff = 262144 + 16384;                          // 278528
    float* partials = (float*)(ws + poff);                 // nb64*132 f32
    size_t roff = poff + (((size_t)nb64 * 132 * 4 + 4095) & ~(size_t)4095);
    float* red  = (float*)(ws + roff);                     // 128*132 f32

    prep_w0  <<<(KPAD * 128 + 255) / 256, 256, 0, stream>>>(W0, Bimg);
    prep_wab <<<64, 256, 0, stream>>>(Wa, Wb, Wab);
    fc_fused <<<nb64, 256, 0, stream>>>(hG, Bimg, Wab, b0, ba, bb, Wc, bc,
                                        partials, N);
    reduce1  <<<128, 256, 0, stream>>>(partials, red, nb64);
    finalize2<<<1, 256, 0, stream>>>(red, Wcls, bcls, (float*)d_out);
}

// Round 9
// 121.294 us; speedup vs baseline: 1.1589x; 1.1589x over previous
//
#include <hip/hip_runtime.h>
#include <stdint.h>
#include <math.h>

typedef unsigned short u16;
typedef unsigned int   u32;
typedef __bf16 bf16x8 __attribute__((ext_vector_type(8)));
typedef float  f32x4  __attribute__((ext_vector_type(4)));

#define L_IN 784
#define KPAD 832
#define KT_N 13

__device__ __forceinline__ u32 f2bf(float f){
    u32 u = __float_as_uint(f);
    return (u + 0x7fffu + ((u >> 16) & 1u)) >> 16;   // RNE truncate to bf16
}

__device__ __forceinline__ void gload16(const void* g, void* l){
    __builtin_amdgcn_global_load_lds(
        (const __attribute__((address_space(1))) unsigned char*)g,
        (__attribute__((address_space(3))) unsigned char*)l, 16, 0, 0);
}

// ---------------------------------------------------------------------------
// K0a: W0 [784][128] f32 -> Bimg in MFMA-fragment-broadcast layout (validated
// r6/r7): Bimg[((kt*2+kk)*8+nt)*512 + lane*8 + j] = W0[k][col] bf16, where
// col = nt*16+(l&15), k = kt*64+kk*32+(l>>4)*8+j. Wave B-load = 1KB contig.
// ---------------------------------------------------------------------------
__global__ void prep_w0(const float* __restrict__ W0, u16* __restrict__ Bimg){
    int idx = blockIdx.x * 256 + threadIdx.x;        // 13*8192 = 106496 total
    if (idx >= KPAD * 128) return;
    int j  = idx & 7;
    int l  = (idx >> 3) & 63;
    int nt = (idx >> 9) & 7;
    int kk = (idx >> 12) & 1;
    int kt = idx >> 13;
    int col = nt * 16 + (l & 15);
    int k   = kt * 64 + kk * 32 + (l >> 4) * 8 + j;
    float v = (k < L_IN) ? W0[k * 128 + col] : 0.f;
    Bimg[idx] = (u16)f2bf(v);
}

// ---------------------------------------------------------------------------
// K0b: Wa/Wb [2][64][32] f32 -> Wab fragment-broadcast bf16 image (validated
// r7). Block b = mat*8 + h*4 + nt*2 + ks: Wab[(b<<9) + l*8 + jj] = W[h][s][d],
//   s = ks*32 + (l>>4)*8 + jj,  d = nt*16 + (l&15).
// ---------------------------------------------------------------------------
__global__ void prep_wab(const float* __restrict__ Wa, const float* __restrict__ Wb,
                         u16* __restrict__ Wab){
    int idx = blockIdx.x * 256 + threadIdx.x;        // 16384 total
    if (idx >= 16384) return;
    int jj  = idx & 7;
    int l   = (idx >> 3) & 63;
    int ks  = (idx >> 9) & 1;
    int nt  = (idx >> 10) & 1;
    int h   = (idx >> 11) & 1;
    int mat = (idx >> 12) & 1;
    int s = ks * 32 + (l >> 4) * 8 + jj;
    int d = nt * 16 + (l & 15);
    const float* W = mat ? Wb : Wa;
    Wab[idx] = (u16)f2bf(W[h * 2048 + s * 32 + d]);
}

// ---------------------------------------------------------------------------
// K1: FUSED x = relu(h@W0+b0) -> gated-attention -> exp -> pooling partials.
// Round-7 structure (validated, 125 us) with ONE change: BOTH B-fragment
// batches are issued BEFORE the next-tile stage. vmcnt retires in order, so
// the deepest pre-MFMA wait is now vmcnt(4) (stage only), and the 4 stage
// DMAs stay in flight under the whole ds_read+cvt+MFMA phase instead of
// being drained by the b1f wait (r7's hidden serializer).
// ---------------------------------------------------------------------------
__global__ __launch_bounds__(256, 4)
void fc_fused(const float* __restrict__ hG, const u16* __restrict__ Bimg,
              const u16* __restrict__ Wab, const float* __restrict__ b0,
              const float* __restrict__ ba, const float* __restrict__ bb,
              const float* __restrict__ Wc, const float* __restrict__ bc,
              float* __restrict__ partials, int N){
    __shared__ __align__(16) float As[2][64 * 64];   // 2 x 16 KB, linear

    const int t    = threadIdx.x;
    const int lane = t & 63;
    const int w    = t >> 6;
    const int lr   = lane & 15;          // A-row / B-col within 16
    const int lk   = lane >> 4;          // k-slot 0..3
    const int gb   = blockIdx.x;
    const long rowBase = (long)gb * 64;

    // ---- staging geometry (round 6/7, validated) ----
    const int rloc = t >> 4;
    const int csw  = (t & 15) ^ ((rloc & 3) << 1);
    const float* srcp[4];
    #pragma unroll
    for (int j = 0; j < 4; ++j){
        long grow = rowBase + j * 16 + rloc;
        if (grow >= N) grow = N - 1;
        srcp[j] = hG + grow * L_IN + csw * 4;
    }

    f32x4 acc[8];
    #pragma unroll
    for (int nt = 0; nt < 8; ++nt) acc[nt] = (f32x4)0.f;

    auto stage = [&](int kt, int buf){
        #pragma unroll
        for (int j = 0; j < 4; ++j){
            const float* src = (kt == KT_N - 1 && csw >= 4)
                             ? (srcp[j] - csw * 4)
                             : (srcp[j] + kt * 64);
            gload16(src, (char*)&As[buf][0] + (j * 256 + t) * 16);
        }
    };

    stage(0, 0);
    int cur = 0;
    const int rA = w * 16 + lr;

    #pragma unroll 1
    for (int kt = 0; kt < KT_N; ++kt){
        __syncthreads();    // drains vmcnt(0): stage(kt) visible in LDS

        // ---- ALL 16 B fragments first (oldest in the vmcnt FIFO) ----
        const u16* bp = Bimg + (size_t)(kt * 2) * 4096 + lane * 8;
        bf16x8 b0f[8], b1f[8];
        #pragma unroll
        for (int nt = 0; nt < 8; ++nt)
            b0f[nt] = *(const bf16x8*)(bp + nt * 512);
        #pragma unroll
        for (int nt = 0; nt < 8; ++nt)
            b1f[nt] = *(const bf16x8*)(bp + 4096 + nt * 512);
        __builtin_amdgcn_sched_barrier(0);

        // ---- stage next tile (youngest: survives every B wait) ----
        if (kt + 1 < KT_N) stage(kt + 1, cur ^ 1);
        __builtin_amdgcn_sched_barrier(0);

        // ---- A from LDS + cvt + MFMA ----
        #pragma unroll
        for (int kk = 0; kk < 2; ++kk){
            const int q = kk * 4 + (lk ^ (rA & 3));
            f32x4 lo = *(const f32x4*)&As[cur][rA * 64 + q * 8];
            f32x4 hi = *(const f32x4*)&As[cur][rA * 64 + q * 8 + 4];
            bf16x8 af;
            #pragma unroll
            for (int j = 0; j < 4; ++j){
                af[j]     = (__bf16)lo[j];
                af[4 + j] = (__bf16)hi[j];
            }
            #pragma unroll
            for (int nt = 0; nt < 8; ++nt)
                acc[nt] = __builtin_amdgcn_mfma_f32_16x16x32_bf16(
                              af, kk ? b1f[nt] : b0f[nt], acc[nt], 0, 0, 0);
        }
        cur ^= 1;
    }

    __syncthreads();   // all waves done reading As -> safe to repurpose LDS

    // ---- bias + relu in place; write x-tile bf16 to LDS (swizzled) ----
    u16*   xs   = (u16*)&As[0][0];        // 64 x 128 bf16 = 16 KB
    float* pbuf = &As[1][0];              // 4 x 132 f32 cross-wave buffer
    #pragma unroll
    for (int nt = 0; nt < 8; ++nt){
        float bias = b0[nt * 16 + lr];
        #pragma unroll
        for (int j = 0; j < 4; ++j){
            float v = acc[nt][j] + bias;
            v = v > 0.f ? v : 0.f;
            acc[nt][j] = v;
            int row = w * 16 + lk * 4 + j;
            int col = nt * 16 + lr;
            xs[row * 128 + ((((col >> 3) ^ (row & 15))) << 3) + (col & 7)] = (u16)f2bf(v);
        }
    }
    __syncthreads();

    // ---- per-head projections via MFMA + logits + exp (validated r7) ----
    float eh[2][4];
    #pragma unroll
    for (int h = 0; h < 2; ++h){
        bf16x8 xa[2];
        #pragma unroll
        for (int ks = 0; ks < 2; ++ks){
            int row = w * 16 + lr;
            int ch  = (h * 8 + ks * 4 + lk) ^ (row & 15);
            xa[ks] = *(const bf16x8*)&xs[row * 128 + ch * 8];
        }
        f32x4 Ca[2], Cg[2];
        #pragma unroll
        for (int nt = 0; nt < 2; ++nt){ Ca[nt] = (f32x4)0.f; Cg[nt] = (f32x4)0.f; }
        #pragma unroll
        for (int nt = 0; nt < 2; ++nt)
            #pragma unroll
            for (int ks = 0; ks < 2; ++ks){
                bf16x8 wfa = *(const bf16x8*)(Wab + ((size_t)(h*4 + nt*2 + ks) << 9) + lane * 8);
                bf16x8 wfb = *(const bf16x8*)(Wab + ((size_t)(8 + h*4 + nt*2 + ks) << 9) + lane * 8);
                Ca[nt] = __builtin_amdgcn_mfma_f32_16x16x32_bf16(xa[ks], wfa, Ca[nt], 0, 0, 0);
                Cg[nt] = __builtin_amdgcn_mfma_f32_16x16x32_bf16(xa[ks], wfb, Cg[nt], 0, 0, 0);
            }
        float pj[4];
        #pragma unroll
        for (int j = 0; j < 4; ++j){
            float s = 0.f;
            #pragma unroll
            for (int nt = 0; nt < 2; ++nt){
                int d = h * 32 + nt * 16 + lr;
                float av = tanhf(Ca[nt][j] + ba[d]);
                float gv = 1.f / (1.f + expf(-(Cg[nt][j] + bb[d])));
                s += av * gv * Wc[d];
            }
            pj[j] = s;
        }
        #pragma unroll
        for (int m = 1; m <= 8; m <<= 1)
            #pragma unroll
            for (int j = 0; j < 4; ++j)
                pj[j] += __shfl_xor(pj[j], m, 64);
        #pragma unroll
        for (int j = 0; j < 4; ++j){
            long row = rowBase + w * 16 + lk * 4 + j;
            // |A| <= sum|Wc|+|bc| (~7): exp safe in f32 without max-subtract
            eh[h][j] = (row < (long)N) ? expf(pj[j] + bc[h]) : 0.f;
        }
    }

    // ---- pooling: p[col] = sum over wave's 16 rows of e*x (f32 acc) ----
    float p[8];
    #pragma unroll
    for (int nt = 0; nt < 8; ++nt){
        const int h = nt >> 2;
        float s = 0.f;
        #pragma unroll
        for (int j = 0; j < 4; ++j) s += eh[h][j] * acc[nt][j];
        p[nt] = s;
    }
    #pragma unroll
    for (int m = 16; m <= 32; m <<= 1)
        #pragma unroll
        for (int nt = 0; nt < 8; ++nt)
            p[nt] += __shfl_xor(p[nt], m, 64);
    float es0 = eh[0][0] + eh[0][1] + eh[0][2] + eh[0][3];
    float es1 = eh[1][0] + eh[1][1] + eh[1][2] + eh[1][3];
    es0 += __shfl_xor(es0, 16, 64); es0 += __shfl_xor(es0, 32, 64);
    es1 += __shfl_xor(es1, 16, 64); es1 += __shfl_xor(es1, 32, 64);

    if (lk == 0){
        #pragma unroll
        for (int nt = 0; nt < 8; ++nt)
            pbuf[w * 132 + nt * 16 + lr] = p[nt];
    }
    if (lane == 0){
        pbuf[w * 132 + 128] = es0;
        pbuf[w * 132 + 129] = es1;
    }
    __syncthreads();
    if (t < 130){
        float s = pbuf[t] + pbuf[132 + t] + pbuf[264 + t] + pbuf[396 + t];
        partials[(size_t)gb * 132 + t] = s;
    }
}

// ---------------------------------------------------------------------------
// K2: first-stage reduction over blocks. 128 blocks x 256 threads.
// ---------------------------------------------------------------------------
__global__ __launch_bounds__(256)
void reduce1(const float* __restrict__ partials, float* __restrict__ red, int nb){
    const int b = blockIdx.x, t = threadIdx.x;
    if (t >= 130) return;
    float a = 0.f;
    for (int r = b; r < nb; r += 128)
        a += partials[(size_t)r * 132 + t];
    red[b * 132 + t] = a;
}

// ---------------------------------------------------------------------------
// K3: combine 128 reduced rows (f64), M, logits, sigmoid, Y_hat. One block.
// ---------------------------------------------------------------------------
__global__ __launch_bounds__(256)
void finalize2(const float* __restrict__ red, const float* __restrict__ Wcls,
               const float* __restrict__ bcls, float* __restrict__ out){
    __shared__ double colD[130];
    __shared__ float  M_s[128];
    const int t = threadIdx.x;
    if (t < 130){
        double s = 0.0;
        for (int r = 0; r < 128; ++r) s += (double)red[r * 132 + t];
        colD[t] = s;
    }
    __syncthreads();
    if (t < 128)
        M_s[t] = (float)(colD[t] / colD[128 + (t >> 6)]);
    __syncthreads();
    if (t == 0){
        double lg = (double)bcls[0];
        for (int c = 0; c < 128; ++c) lg += (double)M_s[c] * (double)Wcls[c];
        float pr = (float)(1.0 / (1.0 + exp(-lg)));
        out[0] = pr;
        out[1] = (lg >= 0.0) ? 1.f : 0.f;
    }
}

// ---------------------------------------------------------------------------
extern "C" void kernel_launch(void* const* d_in, const int* in_sizes, int n_in,
                              void* d_out, int out_size, void* d_ws, size_t ws_size,
                              hipStream_t stream){
    const float* hG   = (const float*)d_in[0];
    const float* W0   = (const float*)d_in[1];
    const float* b0   = (const float*)d_in[2];
    const float* Wa   = (const float*)d_in[3];
    const float* ba   = (const float*)d_in[4];
    const float* Wb   = (const float*)d_in[5];
    const float* bb   = (const float*)d_in[6];
    const float* Wc   = (const float*)d_in[7];
    const float* bc   = (const float*)d_in[8];
    const float* Wcls = (const float*)d_in[9];
    const float* bcls = (const float*)d_in[10];

    const int N    = in_sizes[0] / L_IN;
    const int nb64 = (N + 63) / 64;      // 64-row fused tiles

    char* ws = (char*)d_ws;
    u16* Bimg = (u16*)ws;                                  // 212992 B
    u16* Wab  = (u16*)(ws + 262144);                       // 16384 B
    size_t poff = 262144 + 16384;                          // 278528
    float* partials = (float*)(ws + poff);                 // nb64*132 f32
    size_t roff = poff + (((size_t)nb64 * 132 * 4 + 4095) & ~(size_t)4095);
    float* red  = (float*)(ws + roff);                     // 128*132 f32

    prep_w0  <<<(KPAD * 128 + 255) / 256, 256, 0, stream>>>(W0, Bimg);
    prep_wab <<<64, 256, 0, stream>>>(Wa, Wb, Wab);
    fc_fused <<<nb64, 256, 0, stream>>>(hG, Bimg, Wab, b0, ba, bb, Wc, bc,
                                        partials, N);
    reduce1  <<<128, 256, 0, stream>>>(partials, red, nb64);
    finalize2<<<1, 256, 0, stream>>>(red, Wcls, bcls, (float*)d_out);
}

// Round 10
// 115.333 us; speedup vs baseline: 1.2188x; 1.0517x over previous
//
#include <hip/hip_runtime.h>
#include <stdint.h>
#include <math.h>

typedef unsigned short u16;
typedef unsigned int   u32;
typedef __bf16 bf16x8 __attribute__((ext_vector_type(8)));
typedef float  f32x4  __attribute__((ext_vector_type(4)));

#define L_IN 784
#define KPAD 832
#define KT_N 13

__device__ __forceinline__ u32 f2bf(float f){
    u32 u = __float_as_uint(f);
    return (u + 0x7fffu + ((u >> 16) & 1u)) >> 16;   // RNE truncate to bf16
}

__device__ __forceinline__ void gload16(const void* g, void* l){
    __builtin_amdgcn_global_load_lds(
        (const __attribute__((address_space(1))) unsigned char*)g,
        (__attribute__((address_space(3))) unsigned char*)l, 16, 0, 0);
}

// ---------------------------------------------------------------------------
// K0: merged prep. Part 1: W0 -> Bimg fragment-broadcast bf16 (same layout as
// r6-r9, validated) but with COALESCED reads (idx runs linearly over W0;
// writes scatter, which is latency-tolerant). Part 2: Wa/Wb -> Wab image.
// ---------------------------------------------------------------------------
__global__ void prep_all(const float* __restrict__ W0, const float* __restrict__ Wa,
                         const float* __restrict__ Wb, u16* __restrict__ Bimg,
                         u16* __restrict__ Wab){
    int idx = blockIdx.x * 256 + threadIdx.x;
    if (idx < KPAD * 128){
        int col = idx & 127, k = idx >> 7;
        float v = (k < L_IN) ? W0[idx] : 0.f;        // coalesced (idx = k*128+col)
        int kt = k >> 6, kk = (k >> 5) & 1, j = k & 7, sl = (k >> 3) & 3;
        Bimg[(((kt * 2 + kk) * 8 + (col >> 4)) << 9) + (sl * 16 + (col & 15)) * 8 + j]
            = (u16)f2bf(v);
    } else if (idx < KPAD * 128 + 16384){
        int i2 = idx - KPAD * 128;
        int jj = i2 & 7, l = (i2 >> 3) & 63, ks = (i2 >> 9) & 1;
        int nt = (i2 >> 10) & 1, h = (i2 >> 11) & 1, mat = (i2 >> 12) & 1;
        int s = ks * 32 + (l >> 4) * 8 + jj, d = nt * 16 + (l & 15);
        const float* W = mat ? Wb : Wa;
        Wab[i2] = (u16)f2bf(W[h * 2048 + s * 32 + d]);
    }
}

// ---------------------------------------------------------------------------
// K1: FUSED relu(h@W0+b0) -> gated attention -> exp -> pooling partials.
// r9 structure with a 2-DEEP stage pipeline: 3 LDS buffers; iter kt stages
// kt+2; loop barrier is RAW s_barrier (no vmcnt drain). Correctness: the
// compiler's own counted vmcnt for b0f at iter kt (vmcnt(12): 8 B + 4 stage
// remain) retires stage(kt+1), which is older in the FIFO — so every wave
// enters bar(kt+1) with stage(kt+1) retired; the barrier gives cross-wave
// visibility. kt=0 peeled with a full __syncthreads (one-time drain).
// ---------------------------------------------------------------------------
__global__ __launch_bounds__(256, 3)
void fc_fused(const float* __restrict__ hG, const u16* __restrict__ Bimg,
              const u16* __restrict__ Wab, const float* __restrict__ b0,
              const float* __restrict__ ba, const float* __restrict__ bb,
              const float* __restrict__ Wc, const float* __restrict__ bc,
              float* __restrict__ partials, int N){
    __shared__ __align__(16) char Asm[3 * 16384];    // 3 x 16 KB A buffers

    const int t    = threadIdx.x;
    const int lane = t & 63;
    const int w    = t >> 6;
    const int lr   = lane & 15;          // A-row / B-col within 16
    const int lk   = lane >> 4;          // k-slot 0..3
    const int gb   = blockIdx.x;
    const long rowBase = (long)gb * 64;

    // ---- staging geometry (validated r6-r9) ----
    const int rloc = t >> 4;
    const int csw  = (t & 15) ^ ((rloc & 3) << 1);
    const float* srcp[4];
    #pragma unroll
    for (int j = 0; j < 4; ++j){
        long grow = rowBase + j * 16 + rloc;
        if (grow >= N) grow = N - 1;
        srcp[j] = hG + grow * L_IN + csw * 4;
    }

    f32x4 acc[8];
    #pragma unroll
    for (int nt = 0; nt < 8; ++nt) acc[nt] = (f32x4)0.f;

    auto stage = [&](int kt, char* regn){
        #pragma unroll
        for (int j = 0; j < 4; ++j){
            const float* src = (kt == KT_N - 1 && csw >= 4)
                             ? (srcp[j] - csw * 4)
                             : (srcp[j] + kt * 64);
            gload16(src, regn + (j * 256 + t) * 16);
        }
    };

    char* p0 = &Asm[0];
    char* p1 = &Asm[16384];
    char* p2 = &Asm[32768];
    stage(0, p0);
    stage(1, p1);

    const int rA = w * 16 + lr;

    #pragma unroll 1
    for (int kt = 0; kt < KT_N; ++kt){
        if (kt == 0) __syncthreads();                    // one-time full drain
        else         __builtin_amdgcn_s_barrier();       // raw: no vmcnt drain
        __builtin_amdgcn_sched_barrier(0);

        // ---- all 16 B fragments (oldest group in this iter's FIFO) ----
        const u16* bp = Bimg + (size_t)(kt * 2) * 4096 + lane * 8;
        bf16x8 b0f[8], b1f[8];
        #pragma unroll
        for (int nt = 0; nt < 8; ++nt)
            b0f[nt] = *(const bf16x8*)(bp + nt * 512);
        #pragma unroll
        for (int nt = 0; nt < 8; ++nt)
            b1f[nt] = *(const bf16x8*)(bp + 4096 + nt * 512);
        __builtin_amdgcn_sched_barrier(0);

        // ---- stage tile kt+2 (youngest: survives every B wait) ----
        if (kt + 2 < KT_N) stage(kt + 2, p2);
        __builtin_amdgcn_sched_barrier(0);

        // ---- A from LDS buffer p0 + cvt + MFMA ----
        #pragma unroll
        for (int kk = 0; kk < 2; ++kk){
            const int q = kk * 4 + (lk ^ (rA & 3));
            f32x4 lo = *(const f32x4*)(p0 + (rA * 64 + q * 8) * 4);
            f32x4 hi = *(const f32x4*)(p0 + (rA * 64 + q * 8 + 4) * 4);
            bf16x8 af;
            #pragma unroll
            for (int j = 0; j < 4; ++j){
                af[j]     = (__bf16)lo[j];
                af[4 + j] = (__bf16)hi[j];
            }
            #pragma unroll
            for (int nt = 0; nt < 8; ++nt)
                acc[nt] = __builtin_amdgcn_mfma_f32_16x16x32_bf16(
                              af, kk ? b1f[nt] : b0f[nt], acc[nt], 0, 0, 0);
        }
        // rotate buffers
        char* tmp = p0; p0 = p1; p1 = p2; p2 = tmp;
    }

    __syncthreads();   // full drain; LDS free for reuse

    // ---- bias + relu in place; x-tile bf16 into Asm[0..16K) (swizzled) ----
    u16*   xs   = (u16*)&Asm[0];          // 64 x 128 bf16 = 16 KB
    float* pbuf = (float*)&Asm[16384];    // 4 x 132 f32 cross-wave buffer
    #pragma unroll
    for (int nt = 0; nt < 8; ++nt){
        float bias = b0[nt * 16 + lr];
        #pragma unroll
        for (int j = 0; j < 4; ++j){
            float v = acc[nt][j] + bias;
            v = v > 0.f ? v : 0.f;
            acc[nt][j] = v;
            int row = w * 16 + lk * 4 + j;
            int col = nt * 16 + lr;
            xs[row * 128 + ((((col >> 3) ^ (row & 15))) << 3) + (col & 7)] = (u16)f2bf(v);
        }
    }
    __syncthreads();

    // ---- per-head projections via MFMA + logits + exp (validated r7) ----
    float eh[2][4];
    #pragma unroll
    for (int h = 0; h < 2; ++h){
        bf16x8 xa[2];
        #pragma unroll
        for (int ks = 0; ks < 2; ++ks){
            int row = w * 16 + lr;
            int ch  = (h * 8 + ks * 4 + lk) ^ (row & 15);
            xa[ks] = *(const bf16x8*)&xs[row * 128 + ch * 8];
        }
        f32x4 Ca[2], Cg[2];
        #pragma unroll
        for (int nt = 0; nt < 2; ++nt){ Ca[nt] = (f32x4)0.f; Cg[nt] = (f32x4)0.f; }
        #pragma unroll
        for (int nt = 0; nt < 2; ++nt)
            #pragma unroll
            for (int ks = 0; ks < 2; ++ks){
                bf16x8 wfa = *(const bf16x8*)(Wab + ((size_t)(h*4 + nt*2 + ks) << 9) + lane * 8);
                bf16x8 wfb = *(const bf16x8*)(Wab + ((size_t)(8 + h*4 + nt*2 + ks) << 9) + lane * 8);
                Ca[nt] = __builtin_amdgcn_mfma_f32_16x16x32_bf16(xa[ks], wfa, Ca[nt], 0, 0, 0);
                Cg[nt] = __builtin_amdgcn_mfma_f32_16x16x32_bf16(xa[ks], wfb, Cg[nt], 0, 0, 0);
            }
        float pj[4];
        #pragma unroll
        for (int j = 0; j < 4; ++j){
            float s = 0.f;
            #pragma unroll
            for (int nt = 0; nt < 2; ++nt){
                int d = h * 32 + nt * 16 + lr;
                float av = tanhf(Ca[nt][j] + ba[d]);
                float gv = 1.f / (1.f + expf(-(Cg[nt][j] + bb[d])));
                s += av * gv * Wc[d];
            }
            pj[j] = s;
        }
        #pragma unroll
        for (int m = 1; m <= 8; m <<= 1)
            #pragma unroll
            for (int j = 0; j < 4; ++j)
                pj[j] += __shfl_xor(pj[j], m, 64);
        #pragma unroll
        for (int j = 0; j < 4; ++j){
            long row = rowBase + w * 16 + lk * 4 + j;
            // |A| <= sum|Wc|+|bc| (~7): exp safe in f32 without max-subtract
            eh[h][j] = (row < (long)N) ? expf(pj[j] + bc[h]) : 0.f;
        }
    }

    // ---- pooling: p[col] = sum over wave's 16 rows of e*x (f32 acc) ----
    float p[8];
    #pragma unroll
    for (int nt = 0; nt < 8; ++nt){
        const int h = nt >> 2;
        float s = 0.f;
        #pragma unroll
        for (int j = 0; j < 4; ++j) s += eh[h][j] * acc[nt][j];
        p[nt] = s;
    }
    #pragma unroll
    for (int m = 16; m <= 32; m <<= 1)
        #pragma unroll
        for (int nt = 0; nt < 8; ++nt)
            p[nt] += __shfl_xor(p[nt], m, 64);
    float es0 = eh[0][0] + eh[0][1] + eh[0][2] + eh[0][3];
    float es1 = eh[1][0] + eh[1][1] + eh[1][2] + eh[1][3];
    es0 += __shfl_xor(es0, 16, 64); es0 += __shfl_xor(es0, 32, 64);
    es1 += __shfl_xor(es1, 16, 64); es1 += __shfl_xor(es1, 32, 64);

    if (lk == 0){
        #pragma unroll
        for (int nt = 0; nt < 8; ++nt)
            pbuf[w * 132 + nt * 16 + lr] = p[nt];
    }
    if (lane == 0){
        pbuf[w * 132 + 128] = es0;
        pbuf[w * 132 + 129] = es1;
    }
    __syncthreads();
    if (t < 130){
        float s = pbuf[t] + pbuf[132 + t] + pbuf[264 + t] + pbuf[396 + t];
        partials[(size_t)gb * 132 + t] = s;
    }
}

// ---------------------------------------------------------------------------
// K2: first-stage reduction over blocks. 128 blocks; 2 independent accums.
// ---------------------------------------------------------------------------
__global__ __launch_bounds__(256)
void reduce1(const float* __restrict__ partials, float* __restrict__ red, int nb){
    const int b = blockIdx.x, t = threadIdx.x;
    if (t >= 130) return;
    float a0 = 0.f, a1 = 0.f;
    for (int r = b; r < nb; r += 256){
        a0 += partials[(size_t)r * 132 + t];
        if (r + 128 < nb) a1 += partials[(size_t)(r + 128) * 132 + t];
    }
    red[b * 132 + t] = a0 + a1;
}

// ---------------------------------------------------------------------------
// K3: combine 128 reduced rows (f64), M, logits, sigmoid, Y_hat. One block,
// fully parallel: 2 row-halves x 128 cols, 4-way unrolled independent loads;
// final dot via 64-lane shfl butterfly (fixed order -> deterministic).
// ---------------------------------------------------------------------------
__global__ __launch_bounds__(256)
void finalize2(const float* __restrict__ red, const float* __restrict__ Wcls,
               const float* __restrict__ bcls, float* __restrict__ out){
    __shared__ double colD[2][130];
    __shared__ float  M_s[128];
    const int t = threadIdx.x;
    const int c = t & 127, rh = t >> 7;
    {
        double s = 0.0;
        for (int r = rh * 64; r < rh * 64 + 64; r += 4){
            s += (double)red[(r + 0) * 132 + c] + (double)red[(r + 1) * 132 + c]
               + (double)red[(r + 2) * 132 + c] + (double)red[(r + 3) * 132 + c];
        }
        colD[rh][c] = s;
    }
    if (t < 4){
        int cc = 128 + (t & 1), hh = t >> 1;
        double s = 0.0;
        for (int r = hh * 64; r < hh * 64 + 64; r += 4){
            s += (double)red[(r + 0) * 132 + cc] + (double)red[(r + 1) * 132 + cc]
               + (double)red[(r + 2) * 132 + cc] + (double)red[(r + 3) * 132 + cc];
        }
        colD[hh][cc] = s;
    }
    __syncthreads();
    if (t < 128)
        M_s[t] = (float)((colD[0][t] + colD[1][t]) /
                         (colD[0][128 + (t >> 6)] + colD[1][128 + (t >> 6)]));
    __syncthreads();
    if (t < 64){
        double d = (double)M_s[t] * (double)Wcls[t]
                 + (double)M_s[t + 64] * (double)Wcls[t + 64];
        #pragma unroll
        for (int m = 1; m < 64; m <<= 1) d += __shfl_xor(d, m, 64);
        if (t == 0){
            double lg = d + (double)bcls[0];
            out[0] = (float)(1.0 / (1.0 + exp(-lg)));
            out[1] = (lg >= 0.0) ? 1.f : 0.f;
        }
    }
}

// ---------------------------------------------------------------------------
extern "C" void kernel_launch(void* const* d_in, const int* in_sizes, int n_in,
                              void* d_out, int out_size, void* d_ws, size_t ws_size,
                              hipStream_t stream){
    const float* hG   = (const float*)d_in[0];
    const float* W0   = (const float*)d_in[1];
    const float* b0   = (const float*)d_in[2];
    const float* Wa   = (const float*)d_in[3];
    const float* ba   = (const float*)d_in[4];
    const float* Wb   = (const float*)d_in[5];
    const float* bb   = (const float*)d_in[6];
    const float* Wc   = (const float*)d_in[7];
    const float* bc   = (const float*)d_in[8];
    const float* Wcls = (const float*)d_in[9];
    const float* bcls = (const float*)d_in[10];

    const int N    = in_sizes[0] / L_IN;
    const int nb64 = (N + 63) / 64;      // 64-row fused tiles

    char* ws = (char*)d_ws;
    u16* Bimg = (u16*)ws;                                  // 212992 B
    u16* Wab  = (u16*)(ws + 262144);                       // 16384 B
    size_t poff = 262144 + 16384;                          // 278528
    float* partials = (float*)(ws + poff);                 // nb64*132 f32
    size_t roff = poff + (((size_t)nb64 * 132 * 4 + 4095) & ~(size_t)4095);
    float* red  = (float*)(ws + roff);                     // 128*132 f32

    prep_all <<<(KPAD * 128 + 16384 + 255) / 256, 256, 0, stream>>>(W0, Wa, Wb, Bimg, Wab);
    fc_fused <<<nb64, 256, 0, stream>>>(hG, Bimg, Wab, b0, ba, bb, Wc, bc,
                                        partials, N);
    reduce1  <<<128, 256, 0, stream>>>(partials, red, nb64);
    finalize2<<<1, 256, 0, stream>>>(red, Wcls, bcls, (float*)d_out);
}